// Round 7
// baseline (261.480 us; speedup 1.0000x reference)
//
#include <hip/hip_runtime.h>
#include <hip/hip_bf16.h>

#define NN 200000
#define D 128
#define P 4096
#define R 4
#define T 3
#define K 16

__device__ __forceinline__ float bf2f(unsigned int u) {
    union { unsigned int i; float f; } c;
    c.i = u << 16;
    return c.f;
}
__device__ __forceinline__ unsigned short f2bf(float x) {  // RNE
    union { float f; unsigned int i; } c; c.f = x;
    unsigned int r = c.i + 0x7FFFu + ((c.i >> 16) & 1u);
    return (unsigned short)(r >> 16);
}
__device__ __forceinline__ float ldE(const void* p, size_t i, int f32) {
    return f32 ? ((const float*)p)[i] : bf2f(((const unsigned short*)p)[i]);
}
__device__ __forceinline__ void ld8(const void* p, size_t off, int f32, float* o) {
    if (f32) {
        const float* q = (const float*)p + off;
        float4 a = *(const float4*)q;
        float4 b = *(const float4*)(q + 4);
        o[0]=a.x; o[1]=a.y; o[2]=a.z; o[3]=a.w;
        o[4]=b.x; o[5]=b.y; o[6]=b.z; o[7]=b.w;
    } else {
        uint4 r = *(const uint4*)((const unsigned short*)p + off);
        o[0]=bf2f(r.x & 0xffffu); o[1]=bf2f(r.x >> 16);
        o[2]=bf2f(r.y & 0xffffu); o[3]=bf2f(r.y >> 16);
        o[4]=bf2f(r.z & 0xffffu); o[5]=bf2f(r.z >> 16);
        o[6]=bf2f(r.w & 0xffffu); o[7]=bf2f(r.w >> 16);
    }
}
__device__ __forceinline__ float readlane_f(float v, int lane) {
    return __int_as_float(__builtin_amdgcn_readlane(__float_as_int(v), lane));
}

// Prep: dtype detect (validated r2-r6) + v_t/u_t precompute. Grid = T x 128.
__global__ void prep_kernel(const unsigned short* __restrict__ emb_u,
                            const void* __restrict__ W_phi,
                            const void* __restrict__ W_zeta,
                            int* __restrict__ gflag,
                            float* __restrict__ ws_v, float* __restrict__ ws_u) {
    __shared__ int sbad[2];
    const int tid = threadIdx.x;          // 0..127
    const int t   = blockIdx.x;           // 0..T-1
    int bad = 0;
    #pragma unroll
    for (int i = 0; i < 4; ++i) {
        unsigned short u = emb_u[(size_t)(blockIdx.x * 512 + tid * 4 + i) * 2 * 97];
        unsigned int e = (u >> 7) & 0xFFu;
        if (e >= 147u) bad = 1;
    }
    int anyb = __any(bad) ? 1 : 0;
    if ((tid & 63) == 0) sbad[tid >> 6] = anyb;
    __syncthreads();
    const int f32 = sbad[0] | sbad[1];
    if (t == 0 && tid == 0) *gflag = f32;

    const int d = tid;
    const size_t rb = (size_t)(t * D + d) * D;
    float av = 0.f, au = 0.f;
    for (int e = 0; e < D; e += 8) {
        float w[8], zn[8], zs[8];
        ld8(W_phi, rb + e, f32, w);
        ld8(W_zeta, e, f32, zn);
        ld8(W_zeta, D + e, f32, zs);
        #pragma unroll
        for (int q = 0; q < 8; ++q) { av += w[q] * zn[q]; au += w[q] * zs[q]; }
    }
    ws_v[t * D + d] = av;
    ws_u[t * D + d] = au;
}

// Streaming per-node scores: c[n]=emb[n].v_{t(n)}, c2[n]=emb[n].u_{t(n)}.
// 4 rows in flight per thread (MLP), 16 lanes per row. Grid = NN/64 x 256.
__global__ __launch_bounds__(256) void precompute_c(
    const void* __restrict__ emb, const int* __restrict__ types,
    const float* __restrict__ ws_v, const float* __restrict__ ws_u,
    const int* __restrict__ flag,
    float* __restrict__ c, float* __restrict__ c2)
{
    __shared__ float vsh[T * D], ush[T * D];
    const int f32 = *flag;
    const int tid = threadIdx.x;
    for (int i = tid; i < T * D; i += 256) { vsh[i] = ws_v[i]; ush[i] = ws_u[i]; }
    __syncthreads();
    const int w = tid >> 6, l = tid & 63;
    const int grp = l >> 4, ch = l & 15;
    const int nbase = blockIdx.x * 64 + w * 4 + grp;

    int   tt[4];
    float rv[4][8];
    #pragma unroll
    for (int it = 0; it < 4; ++it) {
        int n = nbase + it * 16;
        tt[it] = types[n];
        ld8(emb, (size_t)n * D + ch * 8, f32, rv[it]);
    }
    #pragma unroll
    for (int it = 0; it < 4; ++it) {
        int n = nbase + it * 16;
        const float* vp = vsh + tt[it] * D + ch * 8;
        const float* up = ush + tt[it] * D + ch * 8;
        float a = 0.f, b = 0.f;
        #pragma unroll
        for (int q = 0; q < 8; ++q) { a += rv[it][q] * vp[q]; b += rv[it][q] * up[q]; }
        #pragma unroll
        for (int off = 1; off <= 8; off <<= 1) {
            a += __shfl_xor(a, off, 64);
            b += __shfl_xor(b, off, 64);
        }
        if (ch == 0) { c[n] = a; c2[n] = b; }
    }
}

// Fused hot kernel: block = 2 pairs x 2 sides; wave = (pair, side).
// Phase 1: alphas in-register (c-table gathers + group softmax).
// Phase 2: column-sliced row gather — scalar-addressed dword loads, no shuffles.
// Then beta-matvec + sigmoid epilogue (round-6-verified).
__global__ __launch_bounds__(256, 4) void fused_all(
    const void* __restrict__ emb,               // (N,D)
    const int* __restrict__ pairs,              // (P,2)
    const int* __restrict__ nbr,                // (P,2,R,K)
    const void* __restrict__ dlt,               // (P,2,R,K)
    const void* __restrict__ W_bw,              // (R,D,D)
    const void* __restrict__ W_bb,              // (R,D)
    const float* __restrict__ c,                // (N,)
    const float* __restrict__ c2,               // (N,)
    const int* __restrict__ flag,
    void* __restrict__ out)                     // (P,D)
{
    __shared__ __align__(16) float gsh[2][2][R][D];   // 16 KB
    __shared__ __align__(16) float ysh[2][2][D];      // 2 KB

    const int f32  = *flag;
    const int tid  = threadIdx.x;
    const int wv   = tid >> 6;
    const int l    = tid & 63;
    const int pr   = wv >> 1;                   // pair within block
    const int s    = wv & 1;                    // side
    const int p    = blockIdx.x * 2 + pr;
    const int rsub = l >> 4;
    const int ch   = l & 15;
    const int base = p * 2 * R * K + s * 64;    // flat (p,s,0,0)

    // ---- Phase 1: alpha for row j=l (r=l>>4, k=l&15), fully in-register.
    const int   nb = nbr[base + l];
    const float dt = ldE(dlt, (size_t)base + l, f32);
    const float ce = c[nb];
    const float es = c2[pairs[p * 2 + s]];
    float e = (ce + es) * __expf(-dt);
    float m = e;
    #pragma unroll
    for (int off = 1; off <= 8; off <<= 1) m = fmaxf(m, __shfl_xor(m, off, 64));
    float al = __expf(e - m);
    float ssum = al;
    #pragma unroll
    for (int off = 1; off <= 8; off <<= 1) ssum += __shfl_xor(ssum, off, 64);
    al *= (1.f / ssum);

    // ---- Phase 2: lane l owns d = {2l, 2l+1}; row index/alpha via readlane (SGPR).
    if (!f32) {
        const unsigned short* eu = (const unsigned short*)emb;
        #pragma unroll
        for (int r = 0; r < R; ++r) {
            unsigned int ud[K];
            #pragma unroll
            for (int k = 0; k < K; ++k) {
                int s_nb = __builtin_amdgcn_readlane(nb, r * K + k);
                ud[k] = *(const unsigned int*)(eu + (size_t)s_nb * D + 2 * l);
            }
            float a0 = 0.f, a1 = 0.f;
            #pragma unroll
            for (int k = 0; k < K; ++k) {
                float a = readlane_f(al, r * K + k);
                a0 += a * bf2f(ud[k] & 0xffffu);
                a1 += a * bf2f(ud[k] >> 16);
            }
            gsh[pr][s][r][2 * l]     = a0;
            gsh[pr][s][r][2 * l + 1] = a1;
        }
    } else {
        const float* ef = (const float*)emb;
        #pragma unroll
        for (int r = 0; r < R; ++r) {
            float2 ud[K];
            #pragma unroll
            for (int k = 0; k < K; ++k) {
                int s_nb = __builtin_amdgcn_readlane(nb, r * K + k);
                ud[k] = *(const float2*)(ef + (size_t)s_nb * D + 2 * l);
            }
            float a0 = 0.f, a1 = 0.f;
            #pragma unroll
            for (int k = 0; k < K; ++k) {
                float a = readlane_f(al, r * K + k);
                a0 += a * ud[k].x;
                a1 += a * ud[k].y;
            }
            gsh[pr][s][r][2 * l]     = a0;
            gsh[pr][s][r][2 * l + 1] = a1;
        }
    }
    __syncthreads();

    // ---- Beta matvec (round-6-verified): wave (pr,s) handles r in {2s, 2s+1}.
    float y[8] = {0.f,0.f,0.f,0.f,0.f,0.f,0.f,0.f};
    const unsigned short* Wu = (const unsigned short*)W_bw;
    #pragma unroll
    for (int rr = 0; rr < 2; ++rr) {
        const int r = s * 2 + rr;
        #pragma unroll 8
        for (int dd = 0; dd < 32; ++dd) {
            const int d = rsub * 32 + dd;
            float gd = gsh[pr][0][r][d] + gsh[pr][1][r][d];
            size_t wo = ((size_t)(r * D + d)) * D + ch * 8;
            if (!f32) {
                uint4 wr = *(const uint4*)(Wu + wo);
                y[0] += gd * bf2f(wr.x & 0xffffu); y[1] += gd * bf2f(wr.x >> 16);
                y[2] += gd * bf2f(wr.y & 0xffffu); y[3] += gd * bf2f(wr.y >> 16);
                y[4] += gd * bf2f(wr.z & 0xffffu); y[5] += gd * bf2f(wr.z >> 16);
                y[6] += gd * bf2f(wr.w & 0xffffu); y[7] += gd * bf2f(wr.w >> 16);
            } else {
                float wb[8]; ld8(W_bw, wo, 1, wb);
                #pragma unroll
                for (int q = 0; q < 8; ++q) y[q] += gd * wb[q];
            }
        }
    }
    #pragma unroll
    for (int q = 0; q < 8; ++q) {
        y[q] += __shfl_xor(y[q], 16, 64);
        y[q] += __shfl_xor(y[q], 32, 64);
    }
    if (rsub == 0) {
        *(float4*)(&ysh[pr][s][ch * 8])     = make_float4(y[0], y[1], y[2], y[3]);
        *(float4*)(&ysh[pr][s][ch * 8 + 4]) = make_float4(y[4], y[5], y[6], y[7]);
    }
    __syncthreads();

    // ---- Epilogue (round-6-verified): s==0, rsub==0 lanes store the 256B row.
    if (s == 0 && rsub == 0) {
        float bs[8] = {0.f,0.f,0.f,0.f,0.f,0.f,0.f,0.f};
        #pragma unroll
        for (int r = 0; r < R; ++r) {
            float bb[8]; ld8(W_bb, (size_t)r * D + ch * 8, f32, bb);
            #pragma unroll
            for (int q = 0; q < 8; ++q) bs[q] += bb[q];
        }
        float o[8];
        #pragma unroll
        for (int q = 0; q < 8; ++q) {
            int e2 = ch * 8 + q;
            float x = (ysh[pr][0][e2] + ysh[pr][1][e2] + 2.f * bs[q]) * 0.125f;
            o[q] = 1.f / (1.f + __expf(-x));
        }
        size_t ob = (size_t)p * D + ch * 8;
        if (f32) {
            *(float4*)((float*)out + ob)     = make_float4(o[0], o[1], o[2], o[3]);
            *(float4*)((float*)out + ob + 4) = make_float4(o[4], o[5], o[6], o[7]);
        } else {
            uint4 pk;
            pk.x = (unsigned int)f2bf(o[0]) | ((unsigned int)f2bf(o[1]) << 16);
            pk.y = (unsigned int)f2bf(o[2]) | ((unsigned int)f2bf(o[3]) << 16);
            pk.z = (unsigned int)f2bf(o[4]) | ((unsigned int)f2bf(o[5]) << 16);
            pk.w = (unsigned int)f2bf(o[6]) | ((unsigned int)f2bf(o[7]) << 16);
            *(uint4*)((unsigned short*)out + ob) = pk;
        }
    }
}

extern "C" void kernel_launch(void* const* d_in, const int* in_sizes, int n_in,
                              void* d_out, int out_size, void* d_ws, size_t ws_size,
                              hipStream_t stream) {
    const void* emb    = d_in[0];
    const int*  pairs  = (const int*)d_in[1];
    const int*  types  = (const int*)d_in[2];
    const int*  nbr    = (const int*)d_in[3];
    const void* dlt    = d_in[4];
    const void* W_phi  = d_in[5];
    const void* W_zeta = d_in[6];
    const void* W_bw   = d_in[7];
    const void* W_bb   = d_in[8];

    int*   flag = (int*)d_ws;                        // bytes [0,256)
    float* ws_v = (float*)d_ws + 64;                 // 384 floats
    float* ws_u = ws_v + T * D;                      // 384 floats
    float* c    = (float*)d_ws + 1024;               // N floats
    float* c2   = c + NN;                            // N floats (~1.6 MB total)

    prep_kernel<<<dim3(T), dim3(128), 0, stream>>>((const unsigned short*)emb,
                                                   W_phi, W_zeta, flag, ws_v, ws_u);
    precompute_c<<<dim3(NN / 64), dim3(256), 0, stream>>>(emb, types, ws_v, ws_u,
                                                          flag, c, c2);
    fused_all<<<dim3(P / 2), dim3(256), 0, stream>>>(emb, pairs, nbr, dlt,
                                                     W_bw, W_bb, c, c2, flag, d_out);
}